// Round 1
// baseline (303.092 us; speedup 1.0000x reference)
//
#include <hip/hip_runtime.h>
#include <cstdint>

// Problem constants (fixed by reference):
// N=4096 windows, T=K+G=33 tokens, C=96, H=6 heads, HD=16, RPE_NUM=51.
// ws layout: qkv[n][s][h][t][d] fp32 : 4096*3*6*33*16 floats = 155,713,536 B.
// K2 overwrites the q slab (s=0) of each window with the attention output
// laid out [t][c] so K3 can read it as the GEMM A matrix.
// Requires ws_size >= 155.7 MB.

static constexpr int NWIN = 4096;
static constexpr int TT   = 33;
static constexpr int MROWS = NWIN * TT;          // 135168 = 1056*128 exactly
static constexpr float SCALE = 0.25f;            // HD^-0.5

__device__ __forceinline__ float dot4(const float4 a, const float4 b) {
  return a.x*b.x + a.y*b.y + a.z*b.z + a.w*b.w;
}
__device__ __forceinline__ void axpy4(float4& o, const float a, const float4 v) {
  o.x += a*v.x; o.y += a*v.y; o.z += a*v.z; o.w += a*v.w;
}

// ---------------- K1: QKV projection GEMM ----------------
// grid (1056, 3), block 256.  data[135168x96] @ qkv_w[96x288] + qkv_b.
// blockIdx.y selects the 96-col slab == s (0:q, 1:k, 2:v). q scaled by 0.25.
__global__ __launch_bounds__(256) void qkv_gemm(
    const float* __restrict__ A, const float* __restrict__ B,
    const float* __restrict__ bias, float* __restrict__ qkv) {
  __shared__ __align__(16) float sA[32*132];   // [k][m] transposed, pad 132
  __shared__ __align__(16) float sB[32*100];   // [k][n], pad 100
  const int tid = threadIdx.x;
  const int rg = tid & 31;        // row group: rows rg*4 .. rg*4+3
  const int cg = tid >> 5;        // col group: cols cg*12 .. cg*12+11
  const int m0 = blockIdx.x * 128;
  const int n0 = blockIdx.y * 96;
  float4 acc[4][3];
  #pragma unroll
  for (int i = 0; i < 4; ++i)
    #pragma unroll
    for (int j = 0; j < 3; ++j) acc[i][j] = make_float4(0.f,0.f,0.f,0.f);

  for (int k0 = 0; k0 < 96; k0 += 32) {
    __syncthreads();
    // stage A chunk (128 rows x 32 k), transposed into sA[k][m]
    for (int idx = tid; idx < 1024; idx += 256) {
      const int row = idx >> 3, qd = idx & 7;
      const float4 v = *(const float4*)(A + (size_t)(m0+row)*96 + k0 + qd*4);
      const int kk = qd*4;
      sA[(kk+0)*132+row] = v.x;
      sA[(kk+1)*132+row] = v.y;
      sA[(kk+2)*132+row] = v.z;
      sA[(kk+3)*132+row] = v.w;
    }
    // stage B chunk (32 k x 96 n)
    for (int idx = tid; idx < 768; idx += 256) {
      const int row = idx / 24, q = idx - row*24;
      *(float4*)&sB[row*100 + q*4] =
          *(const float4*)(B + (size_t)(k0+row)*288 + n0 + q*4);
    }
    __syncthreads();
    #pragma unroll 8
    for (int k = 0; k < 32; ++k) {
      const float4 a  = *(const float4*)&sA[k*132 + rg*4];
      const float4 b0 = *(const float4*)&sB[k*100 + cg*12 + 0];
      const float4 b1 = *(const float4*)&sB[k*100 + cg*12 + 4];
      const float4 b2 = *(const float4*)&sB[k*100 + cg*12 + 8];
      const float av[4] = {a.x, a.y, a.z, a.w};
      #pragma unroll
      for (int i = 0; i < 4; ++i) {
        axpy4(acc[i][0], av[i], b0);
        axpy4(acc[i][1], av[i], b1);
        axpy4(acc[i][2], av[i], b2);
      }
    }
  }
  const int s = blockIdx.y;
  const float sc = (s == 0) ? SCALE : 1.0f;
  #pragma unroll
  for (int i = 0; i < 4; ++i) {
    const int m = m0 + rg*4 + i;
    const int n = m / 33;
    const int t = m - n*33;
    float* wb = qkv + (size_t)n*9504 + (size_t)s*3168 + t*16;
    #pragma unroll
    for (int j = 0; j < 3; ++j) {
      const int cq = cg*12 + j*4;      // col within slab [0,96)
      const int h = cq >> 4, d = cq & 15;
      const float4 bb = *(const float4*)(bias + n0 + cq);
      float4 r;
      r.x = (acc[i][j].x + bb.x)*sc;
      r.y = (acc[i][j].y + bb.y)*sc;
      r.z = (acc[i][j].z + bb.z)*sc;
      r.w = (acc[i][j].w + bb.w)*sc;
      *(float4*)(wb + h*528 + d) = r;
    }
  }
}

// ---------------- K2: per-window attention ----------------
// grid 4096, block 256. One thread per (head,row) pair (198 active).
// Writes attention output over the q slab of the window: [t][c] layout.
__global__ __launch_bounds__(256) void attn_kernel(
    float* __restrict__ qkv, const int* __restrict__ rel,
    const float* __restrict__ mask, const float* __restrict__ rpet) {
  __shared__ __align__(16) float sK[6*33*16];
  __shared__ __align__(16) float sV[6*33*16];
  __shared__ int   sRel[32*97];     // [ri][rj*3+a], row padded to 97
  __shared__ float sMask[33*33];
  __shared__ float sRPE[153*6];
  const int tid = threadIdx.x;
  const int n = blockIdx.x;
  const float4* kb = (const float4*)(qkv + (size_t)n*9504 + 3168);
  const float4* vb = (const float4*)(qkv + (size_t)n*9504 + 6336);
  for (int idx = tid; idx < 792; idx += 256) {
    ((float4*)sK)[idx] = kb[idx];
    ((float4*)sV)[idx] = vb[idx];
  }
  for (int idx = tid; idx < 3072; idx += 256) {
    const int ri = idx / 96, rest = idx - ri*96;
    sRel[ri*97 + rest] = rel[(size_t)n*3072 + idx];
  }
  for (int idx = tid; idx < 1089; idx += 256)
    sMask[idx] = mask[(size_t)n*1089 + idx];
  for (int idx = tid; idx < 918; idx += 256)
    sRPE[idx] = rpet[idx];

  float4 q0, q1, q2, q3;
  int h = 0, i = 0;
  if (tid < 198) {
    h = tid / 33; i = tid - h*33;
    const float4* qb = (const float4*)(qkv + (size_t)n*9504 + h*528 + i*16);
    q0 = qb[0]; q1 = qb[1]; q2 = qb[2]; q3 = qb[3];   // q read BEFORE barrier
  }
  __syncthreads();
  if (tid < 198) {
    float p[33];
    float mx = -3.4e38f;
    #pragma unroll
    for (int j = 0; j < 33; ++j) {
      const float4* kr = (const float4*)&sK[(h*33 + j)*16];
      float lo = dot4(q0,kr[0]) + dot4(q1,kr[1]) + dot4(q2,kr[2]) + dot4(q3,kr[3]);
      lo += sMask[i*33 + j];
      if (i > 0 && j > 0) {
        const int* rp = &sRel[(i-1)*97 + (j-1)*3];
        lo += sRPE[rp[0]*6 + h] + sRPE[(rp[1] + 51)*6 + h] + sRPE[(rp[2] + 102)*6 + h];
      }
      p[j] = lo;
      mx = fmaxf(mx, lo);
    }
    float ssum = 0.f;
    #pragma unroll
    for (int j = 0; j < 33; ++j) { p[j] = __expf(p[j] - mx); ssum += p[j]; }
    const float inv = 1.0f / ssum;
    float4 o0 = make_float4(0.f,0.f,0.f,0.f), o1 = o0, o2 = o0, o3 = o0;
    #pragma unroll
    for (int j = 0; j < 33; ++j) {
      const float pj = p[j];
      const float4* vr = (const float4*)&sV[(h*33 + j)*16];
      axpy4(o0, pj, vr[0]); axpy4(o1, pj, vr[1]);
      axpy4(o2, pj, vr[2]); axpy4(o3, pj, vr[3]);
    }
    o0.x*=inv; o0.y*=inv; o0.z*=inv; o0.w*=inv;
    o1.x*=inv; o1.y*=inv; o1.z*=inv; o1.w*=inv;
    o2.x*=inv; o2.y*=inv; o2.z*=inv; o2.w*=inv;
    o3.x*=inv; o3.y*=inv; o3.z*=inv; o3.w*=inv;
    float* op = qkv + (size_t)n*9504 + (size_t)i*96 + h*16;  // over q slab
    *(float4*)(op + 0) = o0; *(float4*)(op + 4)  = o1;
    *(float4*)(op + 8) = o2; *(float4*)(op + 12) = o3;
  }
}

// ---------------- K3: output projection GEMM ----------------
// grid (1056), block 256.  attnout[135168x96] @ proj_w[96x96] + proj_b.
// A rows live at qkv + n*9504 + t*96 (the overwritten q slabs).
__global__ __launch_bounds__(256) void proj_gemm(
    const float* __restrict__ Aq, const float* __restrict__ B,
    const float* __restrict__ bias, float* __restrict__ out) {
  __shared__ __align__(16) float sA[32*132];
  __shared__ __align__(16) float sB[32*100];
  const int tid = threadIdx.x;
  const int rg = tid & 31;
  const int cg = tid >> 5;
  const int m0 = blockIdx.x * 128;
  float4 acc[4][3];
  #pragma unroll
  for (int i = 0; i < 4; ++i)
    #pragma unroll
    for (int j = 0; j < 3; ++j) acc[i][j] = make_float4(0.f,0.f,0.f,0.f);

  for (int k0 = 0; k0 < 96; k0 += 32) {
    __syncthreads();
    for (int idx = tid; idx < 1024; idx += 256) {
      const int row = idx >> 3, qd = idx & 7;
      const int m = m0 + row;
      const int n = m / 33;
      const int t = m - n*33;
      const float4 v = *(const float4*)(Aq + (size_t)n*9504 + t*96 + k0 + qd*4);
      const int kk = qd*4;
      sA[(kk+0)*132+row] = v.x;
      sA[(kk+1)*132+row] = v.y;
      sA[(kk+2)*132+row] = v.z;
      sA[(kk+3)*132+row] = v.w;
    }
    for (int idx = tid; idx < 768; idx += 256) {
      const int row = idx / 24, q = idx - row*24;
      *(float4*)&sB[row*100 + q*4] =
          *(const float4*)(B + (size_t)(k0+row)*96 + q*4);
    }
    __syncthreads();
    #pragma unroll 8
    for (int k = 0; k < 32; ++k) {
      const float4 a  = *(const float4*)&sA[k*132 + rg*4];
      const float4 b0 = *(const float4*)&sB[k*100 + cg*12 + 0];
      const float4 b1 = *(const float4*)&sB[k*100 + cg*12 + 4];
      const float4 b2 = *(const float4*)&sB[k*100 + cg*12 + 8];
      const float av[4] = {a.x, a.y, a.z, a.w};
      #pragma unroll
      for (int i = 0; i < 4; ++i) {
        axpy4(acc[i][0], av[i], b0);
        axpy4(acc[i][1], av[i], b1);
        axpy4(acc[i][2], av[i], b2);
      }
    }
  }
  #pragma unroll
  for (int i = 0; i < 4; ++i) {
    const int m = m0 + rg*4 + i;
    #pragma unroll
    for (int j = 0; j < 3; ++j) {
      const int cq = cg*12 + j*4;
      const float4 bb = *(const float4*)(bias + cq);
      float4 r;
      r.x = acc[i][j].x + bb.x;
      r.y = acc[i][j].y + bb.y;
      r.z = acc[i][j].z + bb.z;
      r.w = acc[i][j].w + bb.w;
      *(float4*)(out + (size_t)m*96 + cq) = r;
    }
  }
}

extern "C" void kernel_launch(void* const* d_in, const int* in_sizes, int n_in,
                              void* d_out, int out_size, void* d_ws, size_t ws_size,
                              hipStream_t stream) {
  const float* data   = (const float*)d_in[0];
  const int*   rel    = (const int*)  d_in[1];
  const float* mask   = (const float*)d_in[2];
  const float* qkv_w  = (const float*)d_in[3];
  const float* qkv_b  = (const float*)d_in[4];
  const float* proj_w = (const float*)d_in[5];
  const float* proj_b = (const float*)d_in[6];
  const float* rpet   = (const float*)d_in[7];
  float* qkv = (float*)d_ws;            // 155.7 MB scratch
  float* out = (float*)d_out;

  qkv_gemm <<<dim3(MROWS/128, 3), 256, 0, stream>>>(data, qkv_w, qkv_b, qkv);
  attn_kernel<<<dim3(NWIN),       256, 0, stream>>>(qkv, rel, mask, rpet);
  proj_gemm<<<dim3(MROWS/128),    256, 0, stream>>>(qkv, proj_w, proj_b, out);
}

// Round 2
// 265.393 us; speedup vs baseline: 1.1421x; 1.1421x over previous
//
#include <hip/hip_runtime.h>
#include <cstdint>

// Problem constants (fixed by reference):
// N=4096 windows, T=K+G=33 tokens, C=96, H=6 heads, HD=16, RPE_NUM=51.
// ws layout: qkv[n][s][h][t][d] fp32 : 4096*3*6*33*16 floats = 155,713,536 B.
// K2 overwrites the q slab (s=0) of each window with the attention output
// laid out [t][c] so K3 can read it as the GEMM A matrix.
// Requires ws_size >= 155.7 MB.

static constexpr int NWIN = 4096;
static constexpr int TT   = 33;
static constexpr int MROWS = NWIN * TT;          // 135168 = 1056*128 exactly
static constexpr float SCALE = 0.25f;            // HD^-0.5

__device__ __forceinline__ float dot4(const float4 a, const float4 b) {
  return a.x*b.x + a.y*b.y + a.z*b.z + a.w*b.w;
}
__device__ __forceinline__ void axpy4(float4& o, const float a, const float4 v) {
  o.x += a*v.x; o.y += a*v.y; o.z += a*v.z; o.w += a*v.w;
}

// ---------------- K1: QKV projection GEMM ----------------
// grid (1056, 3), block 256.  data[135168x96] @ qkv_w[96x288] + qkv_b.
// blockIdx.y selects the 96-col slab == s (0:q, 1:k, 2:v). q scaled by 0.25.
__global__ __launch_bounds__(256) void qkv_gemm(
    const float* __restrict__ A, const float* __restrict__ B,
    const float* __restrict__ bias, float* __restrict__ qkv) {
  __shared__ __align__(16) float sA[32*132];   // [k][m] transposed, pad 132
  __shared__ __align__(16) float sB[32*100];   // [k][n], pad 100
  const int tid = threadIdx.x;
  const int rg = tid & 31;        // row group: rows rg*4 .. rg*4+3
  const int cg = tid >> 5;        // col group: cols cg*12 .. cg*12+11
  const int m0 = blockIdx.x * 128;
  const int n0 = blockIdx.y * 96;
  float4 acc[4][3];
  #pragma unroll
  for (int i = 0; i < 4; ++i)
    #pragma unroll
    for (int j = 0; j < 3; ++j) acc[i][j] = make_float4(0.f,0.f,0.f,0.f);

  for (int k0 = 0; k0 < 96; k0 += 32) {
    __syncthreads();
    // stage A chunk (128 rows x 32 k), transposed into sA[k][m]
    for (int idx = tid; idx < 1024; idx += 256) {
      const int row = idx >> 3, qd = idx & 7;
      const float4 v = *(const float4*)(A + (size_t)(m0+row)*96 + k0 + qd*4);
      const int kk = qd*4;
      sA[(kk+0)*132+row] = v.x;
      sA[(kk+1)*132+row] = v.y;
      sA[(kk+2)*132+row] = v.z;
      sA[(kk+3)*132+row] = v.w;
    }
    // stage B chunk (32 k x 96 n)
    for (int idx = tid; idx < 768; idx += 256) {
      const int row = idx / 24, q = idx - row*24;
      *(float4*)&sB[row*100 + q*4] =
          *(const float4*)(B + (size_t)(k0+row)*288 + n0 + q*4);
    }
    __syncthreads();
    #pragma unroll 8
    for (int k = 0; k < 32; ++k) {
      const float4 a  = *(const float4*)&sA[k*132 + rg*4];
      const float4 b0 = *(const float4*)&sB[k*100 + cg*12 + 0];
      const float4 b1 = *(const float4*)&sB[k*100 + cg*12 + 4];
      const float4 b2 = *(const float4*)&sB[k*100 + cg*12 + 8];
      const float av[4] = {a.x, a.y, a.z, a.w};
      #pragma unroll
      for (int i = 0; i < 4; ++i) {
        axpy4(acc[i][0], av[i], b0);
        axpy4(acc[i][1], av[i], b1);
        axpy4(acc[i][2], av[i], b2);
      }
    }
  }
  const int s = blockIdx.y;
  const float sc = (s == 0) ? SCALE : 1.0f;
  #pragma unroll
  for (int i = 0; i < 4; ++i) {
    const int m = m0 + rg*4 + i;
    const int n = m / 33;
    const int t = m - n*33;
    float* wb = qkv + (size_t)n*9504 + (size_t)s*3168 + t*16;
    #pragma unroll
    for (int j = 0; j < 3; ++j) {
      const int cq = cg*12 + j*4;      // col within slab [0,96)
      const int h = cq >> 4, d = cq & 15;
      const float4 bb = *(const float4*)(bias + n0 + cq);
      float4 r;
      r.x = (acc[i][j].x + bb.x)*sc;
      r.y = (acc[i][j].y + bb.y)*sc;
      r.z = (acc[i][j].z + bb.z)*sc;
      r.w = (acc[i][j].w + bb.w)*sc;
      *(float4*)(wb + h*528 + d) = r;
    }
  }
}

// ---------------- K2: per-window attention (v2) ----------------
// grid 4096, block 256. One thread per (head,row) pair (198 active).
// LDS diet vs v1: rel_pos packed 3x8bit -> 1 uint (4.2KB vs 12.4KB padded),
// total LDS 37.6KB -> 4 blocks/CU (was 46KB -> 3 blocks/CU).
// Writes attention output over the q slab of the window: [t][c] layout.
__global__ __launch_bounds__(256) void attn_kernel(
    float* __restrict__ qkv, const int* __restrict__ rel,
    const float* __restrict__ mask, const float* __restrict__ rpet) {
  __shared__ __align__(16) float sK[6*33*16];   // 12672 B
  __shared__ __align__(16) float sV[6*33*16];   // 12672 B
  __shared__ float sMask[33*33];                //  4356 B
  __shared__ unsigned int sRelP[32*33];         //  4224 B, [i][j] pad 33
  __shared__ float sRPE[153*6];                 //  3672 B
  const int tid = threadIdx.x;
  const int n = blockIdx.x;
  const float4* kb = (const float4*)(qkv + (size_t)n*9504 + 3168);
  const float4* vb = (const float4*)(qkv + (size_t)n*9504 + 6336);
  for (int idx = tid; idx < 792; idx += 256) {
    ((float4*)sK)[idx] = kb[idx];
    ((float4*)sV)[idx] = vb[idx];
  }
  // rel: 1024 (i,j) pairs, 3 consecutive ints each -> packed byte triple.
  {
    const int* rb = rel + (size_t)n*3072;
    for (int p = tid; p < 1024; p += 256) {
      const int b = p*3;
      const unsigned int v0 = (unsigned int)rb[b];
      const unsigned int v1 = (unsigned int)rb[b+1];
      const unsigned int v2 = (unsigned int)rb[b+2];
      sRelP[(p >> 5)*33 + (p & 31)] = v0 | (v1 << 8) | (v2 << 16);
    }
  }
  for (int idx = tid; idx < 1089; idx += 256)
    sMask[idx] = mask[(size_t)n*1089 + idx];
  for (int idx = tid; idx < 918; idx += 256)
    sRPE[idx] = rpet[idx];

  float4 q0, q1, q2, q3;
  int h = 0, i = 0;
  if (tid < 198) {
    h = tid / 33; i = tid - h*33;
    const float4* qb = (const float4*)(qkv + (size_t)n*9504 + h*528 + i*16);
    q0 = qb[0]; q1 = qb[1]; q2 = qb[2]; q3 = qb[3];   // q read BEFORE barrier
  }
  __syncthreads();
  if (tid < 198) {
    const float* rph = sRPE + h;
    float p[33];
    float mx = -3.4e38f;
    #pragma unroll
    for (int j = 0; j < 33; ++j) {
      const float4* kr = (const float4*)&sK[(h*33 + j)*16];
      float lo = dot4(q0,kr[0]) + dot4(q1,kr[1]) + dot4(q2,kr[2]) + dot4(q3,kr[3]);
      lo += sMask[i*33 + j];
      if (i > 0 && j > 0) {
        const unsigned int pk = sRelP[(i-1)*33 + (j-1)];
        lo += rph[(pk & 0xffu)*6]
            + rph[((pk >> 8) & 0xffu)*6 + 306]
            + rph[((pk >> 16) & 0xffu)*6 + 612];
      }
      p[j] = lo;
      mx = fmaxf(mx, lo);
    }
    float ssum = 0.f;
    #pragma unroll
    for (int j = 0; j < 33; ++j) { p[j] = __expf(p[j] - mx); ssum += p[j]; }
    const float inv = 1.0f / ssum;
    float4 o0 = make_float4(0.f,0.f,0.f,0.f), o1 = o0, o2 = o0, o3 = o0;
    #pragma unroll
    for (int j = 0; j < 33; ++j) {
      const float pj = p[j];
      const float4* vr = (const float4*)&sV[(h*33 + j)*16];
      axpy4(o0, pj, vr[0]); axpy4(o1, pj, vr[1]);
      axpy4(o2, pj, vr[2]); axpy4(o3, pj, vr[3]);
    }
    o0.x*=inv; o0.y*=inv; o0.z*=inv; o0.w*=inv;
    o1.x*=inv; o1.y*=inv; o1.z*=inv; o1.w*=inv;
    o2.x*=inv; o2.y*=inv; o2.z*=inv; o2.w*=inv;
    o3.x*=inv; o3.y*=inv; o3.z*=inv; o3.w*=inv;
    float* op = qkv + (size_t)n*9504 + (size_t)i*96 + h*16;  // over q slab
    *(float4*)(op + 0) = o0; *(float4*)(op + 4)  = o1;
    *(float4*)(op + 8) = o2; *(float4*)(op + 12) = o3;
  }
}

// ---------------- K3: output projection GEMM ----------------
// grid (1056), block 256.  attnout[135168x96] @ proj_w[96x96] + proj_b.
// A rows live at qkv + n*9504 + t*96 (the overwritten q slabs).
__global__ __launch_bounds__(256) void proj_gemm(
    const float* __restrict__ Aq, const float* __restrict__ B,
    const float* __restrict__ bias, float* __restrict__ out) {
  __shared__ __align__(16) float sA[32*132];
  __shared__ __align__(16) float sB[32*100];
  const int tid = threadIdx.x;
  const int rg = tid & 31;
  const int cg = tid >> 5;
  const int m0 = blockIdx.x * 128;
  float4 acc[4][3];
  #pragma unroll
  for (int i = 0; i < 4; ++i)
    #pragma unroll
    for (int j = 0; j < 3; ++j) acc[i][j] = make_float4(0.f,0.f,0.f,0.f);

  for (int k0 = 0; k0 < 96; k0 += 32) {
    __syncthreads();
    for (int idx = tid; idx < 1024; idx += 256) {
      const int row = idx >> 3, qd = idx & 7;
      const int m = m0 + row;
      const int n = m / 33;
      const int t = m - n*33;
      const float4 v = *(const float4*)(Aq + (size_t)n*9504 + t*96 + k0 + qd*4);
      const int kk = qd*4;
      sA[(kk+0)*132+row] = v.x;
      sA[(kk+1)*132+row] = v.y;
      sA[(kk+2)*132+row] = v.z;
      sA[(kk+3)*132+row] = v.w;
    }
    for (int idx = tid; idx < 768; idx += 256) {
      const int row = idx / 24, q = idx - row*24;
      *(float4*)&sB[row*100 + q*4] =
          *(const float4*)(B + (size_t)(k0+row)*96 + q*4);
    }
    __syncthreads();
    #pragma unroll 8
    for (int k = 0; k < 32; ++k) {
      const float4 a  = *(const float4*)&sA[k*132 + rg*4];
      const float4 b0 = *(const float4*)&sB[k*100 + cg*12 + 0];
      const float4 b1 = *(const float4*)&sB[k*100 + cg*12 + 4];
      const float4 b2 = *(const float4*)&sB[k*100 + cg*12 + 8];
      const float av[4] = {a.x, a.y, a.z, a.w};
      #pragma unroll
      for (int i = 0; i < 4; ++i) {
        axpy4(acc[i][0], av[i], b0);
        axpy4(acc[i][1], av[i], b1);
        axpy4(acc[i][2], av[i], b2);
      }
    }
  }
  #pragma unroll
  for (int i = 0; i < 4; ++i) {
    const int m = m0 + rg*4 + i;
    #pragma unroll
    for (int j = 0; j < 3; ++j) {
      const int cq = cg*12 + j*4;
      const float4 bb = *(const float4*)(bias + cq);
      float4 r;
      r.x = acc[i][j].x + bb.x;
      r.y = acc[i][j].y + bb.y;
      r.z = acc[i][j].z + bb.z;
      r.w = acc[i][j].w + bb.w;
      *(float4*)(out + (size_t)m*96 + cq) = r;
    }
  }
}

extern "C" void kernel_launch(void* const* d_in, const int* in_sizes, int n_in,
                              void* d_out, int out_size, void* d_ws, size_t ws_size,
                              hipStream_t stream) {
  const float* data   = (const float*)d_in[0];
  const int*   rel    = (const int*)  d_in[1];
  const float* mask   = (const float*)d_in[2];
  const float* qkv_w  = (const float*)d_in[3];
  const float* qkv_b  = (const float*)d_in[4];
  const float* proj_w = (const float*)d_in[5];
  const float* proj_b = (const float*)d_in[6];
  const float* rpet   = (const float*)d_in[7];
  float* qkv = (float*)d_ws;            // 155.7 MB scratch
  float* out = (float*)d_out;

  qkv_gemm <<<dim3(MROWS/128, 3), 256, 0, stream>>>(data, qkv_w, qkv_b, qkv);
  attn_kernel<<<dim3(NWIN),       256, 0, stream>>>(qkv, rel, mask, rpet);
  proj_gemm<<<dim3(MROWS/128),    256, 0, stream>>>(qkv, proj_w, proj_b, out);
}

// Round 3
// 194.981 us; speedup vs baseline: 1.5545x; 1.3611x over previous
//
#include <hip/hip_runtime.h>
#include <cstdint>

// N=4096 windows, T=33, C=96, H=6, HD=16.
// ws layout: qkv[n][s][h][t][d] fp32 : 4096*3*6*33*16 floats = 155,713,536 B (proven fit).
// GEMMs run on MFMA 16x16x32 bf16 with split-precision (hi+lo), 3 MFMAs per tile:
//   C = Ah*Bh + Al*Bh + Ah*Bl   (Al*Bl dropped, ~2^-18 relative)
// Weight B-fragments are precomputed into scratch:
//   qkv_w frags (108 frags x 1KB = 110,592 B) -> start of d_out (overwritten by K3 later)
//   proj_w frags (36 frags x 1KB = 36,864 B)  -> dead k/v slabs of windows 0,1 in ws (after attn)
// Frag layout: frag fp, lane l, dword d holds bf16x2 of W[k][n], k = kstep*32+(l>>4)*8+2d(+1),
//   n = cf*16 + (l&15); dword index = fp*256 + l*4 + d.

static constexpr int NWIN = 4096;
static constexpr int MROWS = NWIN * 33;          // 135168 = 1056*128
static constexpr float SCALE = 0.25f;            // HD^-0.5

using short8 = __attribute__((ext_vector_type(8))) short;
using f32x4  = __attribute__((ext_vector_type(4))) float;

__device__ __forceinline__ unsigned short f2bf(float f) {
  unsigned u = __float_as_uint(f);
  u += 0x7fffu + ((u >> 16) & 1u);
  return (unsigned short)(u >> 16);
}
__device__ __forceinline__ float bf2f(unsigned short h) {
  return __uint_as_float(((unsigned)h) << 16);
}
__device__ __forceinline__ float dot4(const float4 a, const float4 b) {
  return a.x*b.x + a.y*b.y + a.z*b.z + a.w*b.w;
}
__device__ __forceinline__ void axpy4(float4& o, const float a, const float4 v) {
  o.x += a*v.x; o.y += a*v.y; o.z += a*v.z; o.w += a*v.w;
}

// ---------------- K0: qkv_w -> B-fragments in d_out ----------------
// grid 108 (= 3 ksteps * 18 colfrags * 2 hi/lo), block 256.
__global__ __launch_bounds__(256) void conv_w_qkv(
    const float* __restrict__ W, unsigned* __restrict__ frag) {
  const int fp = blockIdx.x;
  const int kstep = fp / 36;
  const int r = fp - kstep*36;
  const int cf = r >> 1, hl = r & 1;
  const int t = threadIdx.x, lane = t >> 2, d = t & 3;
  const int k = kstep*32 + (lane >> 4)*8 + d*2;
  const int n = cf*16 + (lane & 15);
  float w0 = W[k*288 + n], w1 = W[(k+1)*288 + n];
  if (hl) { w0 -= bf2f(f2bf(w0)); w1 -= bf2f(f2bf(w1)); }
  frag[fp*256 + t] = (unsigned)f2bf(w0) | ((unsigned)f2bf(w1) << 16);
}

// ---------------- K2b: proj_w -> B-fragments in dead k/v slabs of ws ----
// grid 36 (= 3 ksteps * 6 colfrags * 2), block 256. Runs AFTER attn.
__global__ __launch_bounds__(256) void conv_w_proj(
    const float* __restrict__ W, unsigned* __restrict__ qkvU) {
  const int fp = blockIdx.x;
  const int kstep = fp / 12;
  const int r = fp - kstep*12;
  const int cf = r >> 1, hl = r & 1;
  const int t = threadIdx.x, lane = t >> 2, d = t & 3;
  const int k = kstep*32 + (lane >> 4)*8 + d*2;
  const int n = cf*16 + (lane & 15);
  float w0 = W[k*96 + n], w1 = W[(k+1)*96 + n];
  if (hl) { w0 -= bf2f(f2bf(w0)); w1 -= bf2f(f2bf(w1)); }
  const int i = fp*256 + t;                       // dword index 0..9215
  qkvU[i + (i < 6336 ? 3168 : 6336)] =            // win0/win1 k+v slabs
      (unsigned)f2bf(w0) | ((unsigned)f2bf(w1) << 16);
}

// ---------------- K1: QKV projection, split-bf16 MFMA ----------------
// grid (1056, 3), block 256 (4 waves). Wave w: rows w*32..+31 (2 rowfrags).
__global__ __launch_bounds__(256) void qkv_mfma(
    const float* __restrict__ A, const unsigned* __restrict__ frag,
    const float* __restrict__ bias, float* __restrict__ qkv) {
  __shared__ __align__(16) unsigned short sAh[128*104];
  __shared__ __align__(16) unsigned short sAl[128*104];
  const int tid = threadIdx.x;
  const int w = tid >> 6, l = tid & 63;
  const int m0 = blockIdx.x * 128;
  const int s = blockIdx.y;
  // stage A (128 x 96) as hi/lo bf16, row stride 104 (2-way-free banks)
  for (int idx = tid; idx < 3072; idx += 256) {
    const int row = idx / 24, q = idx - row*24;
    const float4 v = *(const float4*)(A + (size_t)(m0+row)*96 + q*4);
    ushort4 hv, lv;
    hv.x = f2bf(v.x); hv.y = f2bf(v.y); hv.z = f2bf(v.z); hv.w = f2bf(v.w);
    lv.x = f2bf(v.x - bf2f(hv.x)); lv.y = f2bf(v.y - bf2f(hv.y));
    lv.z = f2bf(v.z - bf2f(hv.z)); lv.w = f2bf(v.w - bf2f(hv.w));
    *(ushort4*)&sAh[row*104 + q*4] = hv;
    *(ushort4*)&sAl[row*104 + q*4] = lv;
  }
  __syncthreads();
  f32x4 acc[2][6];
  #pragma unroll
  for (int rf = 0; rf < 2; ++rf)
    #pragma unroll
    for (int cf = 0; cf < 6; ++cf) acc[rf][cf] = (f32x4){0.f,0.f,0.f,0.f};

  #pragma unroll
  for (int kstep = 0; kstep < 3; ++kstep) {
    short8 bh[6], bl[6];
    #pragma unroll
    for (int cf = 0; cf < 6; ++cf) {
      const int fp = (kstep*18 + s*6 + cf)*2;
      bh[cf] = *(const short8*)((const char*)frag + (size_t)fp*1024 + l*16);
      bl[cf] = *(const short8*)((const char*)frag + (size_t)fp*1024 + 1024 + l*16);
    }
    #pragma unroll
    for (int rf = 0; rf < 2; ++rf) {
      const int row = w*32 + rf*16 + (l & 15);
      const int off = row*104 + kstep*32 + (l >> 4)*8;
      const short8 ah = *(const short8*)&sAh[off];
      const short8 al = *(const short8*)&sAl[off];
      #pragma unroll
      for (int cf = 0; cf < 6; ++cf) {
        acc[rf][cf] = __builtin_amdgcn_mfma_f32_16x16x32_bf16(ah, bh[cf], acc[rf][cf], 0,0,0);
        acc[rf][cf] = __builtin_amdgcn_mfma_f32_16x16x32_bf16(al, bh[cf], acc[rf][cf], 0,0,0);
        acc[rf][cf] = __builtin_amdgcn_mfma_f32_16x16x32_bf16(ah, bl[cf], acc[rf][cf], 0,0,0);
      }
    }
  }
  // epilogue: +bias, scale q, scatter to qkv[n][s][h][t][d]
  const float sc = (s == 0) ? SCALE : 1.0f;
  const int col = l & 15;
  #pragma unroll
  for (int cf = 0; cf < 6; ++cf) {
    const float bv = bias[s*96 + cf*16 + col];
    #pragma unroll
    for (int rf = 0; rf < 2; ++rf) {
      #pragma unroll
      for (int r = 0; r < 4; ++r) {
        const int m = m0 + w*32 + rf*16 + (l >> 4)*4 + r;
        const int n = m / 33, t = m - n*33;
        qkv[(size_t)n*9504 + s*3168 + cf*528 + t*16 + col] = (acc[rf][cf][r] + bv)*sc;
      }
    }
  }
}

// ---------------- K2: per-window attention (unchanged from round 2) ----
__global__ __launch_bounds__(256) void attn_kernel(
    float* __restrict__ qkv, const int* __restrict__ rel,
    const float* __restrict__ mask, const float* __restrict__ rpet) {
  __shared__ __align__(16) float sK[6*33*16];
  __shared__ __align__(16) float sV[6*33*16];
  __shared__ float sMask[33*33];
  __shared__ unsigned int sRelP[32*33];
  __shared__ float sRPE[153*6];
  const int tid = threadIdx.x;
  const int n = blockIdx.x;
  const float4* kb = (const float4*)(qkv + (size_t)n*9504 + 3168);
  const float4* vb = (const float4*)(qkv + (size_t)n*9504 + 6336);
  for (int idx = tid; idx < 792; idx += 256) {
    ((float4*)sK)[idx] = kb[idx];
    ((float4*)sV)[idx] = vb[idx];
  }
  {
    const int* rb = rel + (size_t)n*3072;
    for (int p = tid; p < 1024; p += 256) {
      const int b = p*3;
      const unsigned int v0 = (unsigned int)rb[b];
      const unsigned int v1 = (unsigned int)rb[b+1];
      const unsigned int v2 = (unsigned int)rb[b+2];
      sRelP[(p >> 5)*33 + (p & 31)] = v0 | (v1 << 8) | (v2 << 16);
    }
  }
  for (int idx = tid; idx < 1089; idx += 256)
    sMask[idx] = mask[(size_t)n*1089 + idx];
  for (int idx = tid; idx < 918; idx += 256)
    sRPE[idx] = rpet[idx];

  float4 q0, q1, q2, q3;
  int h = 0, i = 0;
  if (tid < 198) {
    h = tid / 33; i = tid - h*33;
    const float4* qb = (const float4*)(qkv + (size_t)n*9504 + h*528 + i*16);
    q0 = qb[0]; q1 = qb[1]; q2 = qb[2]; q3 = qb[3];
  }
  __syncthreads();
  if (tid < 198) {
    const float* rph = sRPE + h;
    float p[33];
    float mx = -3.4e38f;
    #pragma unroll
    for (int j = 0; j < 33; ++j) {
      const float4* kr = (const float4*)&sK[(h*33 + j)*16];
      float lo = dot4(q0,kr[0]) + dot4(q1,kr[1]) + dot4(q2,kr[2]) + dot4(q3,kr[3]);
      lo += sMask[i*33 + j];
      if (i > 0 && j > 0) {
        const unsigned int pk = sRelP[(i-1)*33 + (j-1)];
        lo += rph[(pk & 0xffu)*6]
            + rph[((pk >> 8) & 0xffu)*6 + 306]
            + rph[((pk >> 16) & 0xffu)*6 + 612];
      }
      p[j] = lo;
      mx = fmaxf(mx, lo);
    }
    float ssum = 0.f;
    #pragma unroll
    for (int j = 0; j < 33; ++j) { p[j] = __expf(p[j] - mx); ssum += p[j]; }
    const float inv = 1.0f / ssum;
    float4 o0 = make_float4(0.f,0.f,0.f,0.f), o1 = o0, o2 = o0, o3 = o0;
    #pragma unroll
    for (int j = 0; j < 33; ++j) {
      const float pj = p[j];
      const float4* vr = (const float4*)&sV[(h*33 + j)*16];
      axpy4(o0, pj, vr[0]); axpy4(o1, pj, vr[1]);
      axpy4(o2, pj, vr[2]); axpy4(o3, pj, vr[3]);
    }
    o0.x*=inv; o0.y*=inv; o0.z*=inv; o0.w*=inv;
    o1.x*=inv; o1.y*=inv; o1.z*=inv; o1.w*=inv;
    o2.x*=inv; o2.y*=inv; o2.z*=inv; o2.w*=inv;
    o3.x*=inv; o3.y*=inv; o3.z*=inv; o3.w*=inv;
    float* op = qkv + (size_t)n*9504 + (size_t)i*96 + h*16;  // over q slab
    *(float4*)(op + 0) = o0; *(float4*)(op + 4)  = o1;
    *(float4*)(op + 8) = o2; *(float4*)(op + 12) = o3;
  }
}

// ---------------- K3: output projection, split-bf16 MFMA ----------------
// grid 1056, block 256. A = attn output in q-slabs; B-frags from ws k/v scratch.
__global__ __launch_bounds__(256) void proj_mfma(
    const float* __restrict__ qkv, const float* __restrict__ bias,
    float* __restrict__ out) {
  __shared__ __align__(16) unsigned short sAh[128*104];
  __shared__ __align__(16) unsigned short sAl[128*104];
  const int tid = threadIdx.x;
  const int w = tid >> 6, l = tid & 63;
  const int m0 = blockIdx.x * 128;
  const unsigned* qkvU = (const unsigned*)qkv;
  for (int idx = tid; idx < 3072; idx += 256) {
    const int row = idx / 24, q = idx - row*24;
    const int m = m0 + row;
    const int n = m / 33, t = m - n*33;
    const float4 v = *(const float4*)(qkv + (size_t)n*9504 + t*96 + q*4);
    ushort4 hv, lv;
    hv.x = f2bf(v.x); hv.y = f2bf(v.y); hv.z = f2bf(v.z); hv.w = f2bf(v.w);
    lv.x = f2bf(v.x - bf2f(hv.x)); lv.y = f2bf(v.y - bf2f(hv.y));
    lv.z = f2bf(v.z - bf2f(hv.z)); lv.w = f2bf(v.w - bf2f(hv.w));
    *(ushort4*)&sAh[row*104 + q*4] = hv;
    *(ushort4*)&sAl[row*104 + q*4] = lv;
  }
  __syncthreads();
  f32x4 acc[2][6];
  #pragma unroll
  for (int rf = 0; rf < 2; ++rf)
    #pragma unroll
    for (int cf = 0; cf < 6; ++cf) acc[rf][cf] = (f32x4){0.f,0.f,0.f,0.f};

  #pragma unroll
  for (int kstep = 0; kstep < 3; ++kstep) {
    short8 bh[6], bl[6];
    #pragma unroll
    for (int cf = 0; cf < 6; ++cf) {
      const int fph = kstep*12 + cf*2;
      const int i0 = fph*256 + l*4;
      const int i1 = i0 + 256;
      bh[cf] = *(const short8*)(qkvU + i0 + (i0 < 6336 ? 3168 : 6336));
      bl[cf] = *(const short8*)(qkvU + i1 + (i1 < 6336 ? 3168 : 6336));
    }
    #pragma unroll
    for (int rf = 0; rf < 2; ++rf) {
      const int row = w*32 + rf*16 + (l & 15);
      const int off = row*104 + kstep*32 + (l >> 4)*8;
      const short8 ah = *(const short8*)&sAh[off];
      const short8 al = *(const short8*)&sAl[off];
      #pragma unroll
      for (int cf = 0; cf < 6; ++cf) {
        acc[rf][cf] = __builtin_amdgcn_mfma_f32_16x16x32_bf16(ah, bh[cf], acc[rf][cf], 0,0,0);
        acc[rf][cf] = __builtin_amdgcn_mfma_f32_16x16x32_bf16(al, bh[cf], acc[rf][cf], 0,0,0);
        acc[rf][cf] = __builtin_amdgcn_mfma_f32_16x16x32_bf16(ah, bl[cf], acc[rf][cf], 0,0,0);
      }
    }
  }
  const int col = l & 15;
  #pragma unroll
  for (int cf = 0; cf < 6; ++cf) {
    const float bv = bias[cf*16 + col];
    #pragma unroll
    for (int rf = 0; rf < 2; ++rf) {
      #pragma unroll
      for (int r = 0; r < 4; ++r) {
        const int m = m0 + w*32 + rf*16 + (l >> 4)*4 + r;
        out[(size_t)m*96 + cf*16 + col] = acc[rf][cf][r] + bv;
      }
    }
  }
}

extern "C" void kernel_launch(void* const* d_in, const int* in_sizes, int n_in,
                              void* d_out, int out_size, void* d_ws, size_t ws_size,
                              hipStream_t stream) {
  const float* data   = (const float*)d_in[0];
  const int*   rel    = (const int*)  d_in[1];
  const float* mask   = (const float*)d_in[2];
  const float* qkv_w  = (const float*)d_in[3];
  const float* qkv_b  = (const float*)d_in[4];
  const float* proj_w = (const float*)d_in[5];
  const float* proj_b = (const float*)d_in[6];
  const float* rpet   = (const float*)d_in[7];
  float* qkv = (float*)d_ws;            // 155.7 MB scratch (as before)
  float* out = (float*)d_out;

  conv_w_qkv<<<dim3(108),        256, 0, stream>>>(qkv_w, (unsigned*)d_out);
  qkv_mfma  <<<dim3(MROWS/128,3),256, 0, stream>>>(data, (const unsigned*)d_out, qkv_b, qkv);
  attn_kernel<<<dim3(NWIN),      256, 0, stream>>>(qkv, rel, mask, rpet);
  conv_w_proj<<<dim3(36),        256, 0, stream>>>(proj_w, (unsigned*)qkv);
  proj_mfma <<<dim3(MROWS/128),  256, 0, stream>>>(qkv, proj_b, out);
}